// Round 7
// baseline (161.186 us; speedup 1.0000x reference)
//
#include <hip/hip_runtime.h>
#include <math.h>

#define H 4096
#define W 4096
#define NC 512            // cells per dim (H/8)
#define NB 510            // blocks per dim (NC - 3 + 1)
#define ORI 9
#define NCELLS (NC * NC)  // 262144
#define NOUT (NB * NB * 81)  // 21068100

// ---- glibc flt-32 atanf/atan2f replication (fdlibm; pre-2.40 glibc) ----
// Used only on the rare near-boundary fallback path; must stay bit-exact.
__device__ __constant__ float c_atanhi[4] = {
    4.6364760399e-01f, 7.8539812565e-01f, 9.8279368877e-01f, 1.5707962513e+00f,
};
__device__ __constant__ float c_atanlo[4] = {
    5.0121582440e-09f, 3.7748947079e-08f, 3.4473217170e-08f, 7.5497894159e-08f,
};

__device__ float fdlibm_atanf(float x) {
#pragma clang fp contract(off)
    const float one = 1.0f;
    const float aT0  = (float) 3.33333333333329318027e-01;
    const float aT1  = (float)-1.99999999998764832476e-01;
    const float aT2  = (float) 1.42857142725034663711e-01;
    const float aT3  = (float)-1.11111104054623557880e-01;
    const float aT4  = (float) 9.09088713343650656196e-02;
    const float aT5  = (float)-7.69187620504482999495e-02;
    const float aT6  = (float) 6.66107313738753120669e-02;
    const float aT7  = (float)-5.83357013379057348645e-02;
    const float aT8  = (float) 4.97687799461593236017e-02;
    const float aT9  = (float)-3.65315727442169155270e-02;
    const float aT10 = (float) 1.62858201153657823623e-02;
    int hx = __float_as_int(x);
    int ix = hx & 0x7fffffff;
    int id;
    if (ix >= 0x4c800000) {
        if (ix > 0x7f800000) return x + x;
        float r = c_atanhi[3] + c_atanlo[3];
        return (hx > 0) ? r : -r;
    }
    if (ix < 0x3ee00000) {
        if (ix < 0x31000000) return x;
        id = -1;
    } else {
        x = fabsf(x);
        if (ix < 0x3f980000) {
            if (ix < 0x3f300000) { id = 0; x = (2.0f * x - one) / (2.0f + x); }
            else                 { id = 1; x = (x - one) / (x + one); }
        } else {
            if (ix < 0x401c0000) { id = 2; x = (x - 1.5f) / (one + 1.5f * x); }
            else                 { id = 3; x = -1.0f / x; }
        }
    }
    float z = x * x;
    float w = z * z;
    float s1 = z * (aT0 + w * (aT2 + w * (aT4 + w * (aT6 + w * (aT8 + w * aT10)))));
    float s2 = w * (aT1 + w * (aT3 + w * (aT5 + w * (aT7 + w * aT9))));
    if (id < 0) return x - x * (s1 + s2);
    z = c_atanhi[id] - ((x * (s1 + s2) - c_atanlo[id]) - x);
    return (hx < 0) ? -z : z;
}

__device__ float fdlibm_atan2f(float y, float x) {
#pragma clang fp contract(off)
    const float tiny   = 1.0e-30f;
    const float pi     = 3.1415927410e+00f;
    const float pi_lo  = -8.7422776573e-08f;
    const float pi_o_2 = 1.5707963705e+00f;
    int hx = __float_as_int(x), ix = hx & 0x7fffffff;
    int hy = __float_as_int(y), iy = hy & 0x7fffffff;
    if (ix > 0x7f800000 || iy > 0x7f800000) return x + y;
    if (hx == 0x3f800000) return fdlibm_atanf(y);
    int m = ((hy >> 31) & 1) | ((hx >> 30) & 2);
    if (iy == 0) {
        switch (m) {
            case 0: case 1: return y;
            case 2: return pi + tiny;
            default: return -pi - tiny;
        }
    }
    if (ix == 0) return (hy < 0) ? -pi_o_2 - tiny : pi_o_2 + tiny;
    if (ix == 0x7f800000) {
        if (iy == 0x7f800000) {
            switch (m) {
                case 0: return pi_o_2 * 0.5f + tiny;
                case 1: return -(pi_o_2 * 0.5f) - tiny;
                case 2: return 1.5f * pi_o_2 + tiny;
                default: return -(1.5f * pi_o_2) - tiny;
            }
        } else {
            switch (m) {
                case 0: return 0.0f;
                case 1: return -0.0f;
                case 2: return pi + tiny;
                default: return -pi - tiny;
            }
        }
    }
    if (iy == 0x7f800000) return (hy < 0) ? -pi_o_2 - tiny : pi_o_2 + tiny;
    int k = (iy - ix) >> 23;
    float z;
    if (k > 26) { z = pi_o_2 + 0.5f * pi_lo; m &= 1; }
    else if (k < -26 && hx < 0) z = 0.0f;
    else z = fdlibm_atanf(fabsf(y / x));
    switch (m) {
        case 0: return z;
        case 1: return -z;
        case 2: return pi - (z - pi_lo);
        default: return (z - pi_lo) - pi;
    }
}

// Exact-replica binning (slow path). Returns 0..8, or 9 == excluded (m==180 quirk).
__device__ __noinline__ int slow_bin(float gy, float gx) {
#pragma clang fp contract(off)
    float ang = fdlibm_atan2f(gy, gx);
    const float RAD2DEG = (float)(180.0 / 3.14159265358979323846264338328);
    float deg = ang * RAD2DEG;
    float m = fmodf(deg, 180.0f);
    if (m < 0.0f) m += 180.0f;
    int bin = (int)(m / 20.0f);
    if (bin < 9 && m >= (float)((bin + 1) * 20)) bin++;
    else if (bin > 0 && m < (float)(bin * 20)) bin--;
    return bin;
}

// Fast branchless bin via 8 half-plane sign tests; falls back to the
// bit-exact replica near boundaries / near-horizontal gradients.
__device__ __forceinline__ int bin_pixel(float gy, float gx) {
    const float C1 = (float) 0.93969262078590838405, S1 = (float) 0.34202014332566873304;
    const float C2 = (float) 0.76604444311897803520, S2 = (float) 0.64278760968653932632;
    const float C3 = 0.5f,                           S3 = (float) 0.86602540378443864676;
    const float C4 = (float) 0.17364817766693034885, S4 = (float) 0.98480775301220805937;
    float cr1 = fmaf(gy, C1, -gx * S1);
    float cr2 = fmaf(gy, C2, -gx * S2);
    float cr3 = fmaf(gy, C3, -gx * S3);
    float cr4 = fmaf(gy, C4, -gx * S4);
    float cr5 = fmaf(gy, -C4, -gx * S4);
    float cr6 = fmaf(gy, -C3, -gx * S3);
    float cr7 = fmaf(gy, -C2, -gx * S2);
    float cr8 = fmaf(gy, -C1, -gx * S1);
    int cnt = (cr1 >= 0.0f) + (cr2 >= 0.0f) + (cr3 >= 0.0f) + (cr4 >= 0.0f)
            + (cr5 >= 0.0f) + (cr6 >= 0.0f) + (cr7 >= 0.0f) + (cr8 >= 0.0f);
    int bin = (gy < 0.0f) ? 8 - cnt : cnt;
    float ay = fabsf(gy), ax = fabsf(gx);
    float r = ax + ay;
    float cm = fminf(fminf(fminf(fabsf(cr1), fabsf(cr2)), fminf(fabsf(cr3), fabsf(cr4))),
                     fminf(fminf(fabsf(cr5), fabsf(cr6)), fminf(fabsf(cr7), fabsf(cr8))));
    const float EPSA = 1e-5f;
    if (fminf(cm, ay) < EPSA * r) bin = slow_bin(gy, gx);
    return bin;
}

// Kernel A: wave = 64 columns x 8 rows = 512 px = one row of 8 cells.
// Lane owns a column of 8 px in registers (10-row load incl halo).
// gy in-register; gx via lane shuffles + broadcast halo columns.
// Per-wave private LDS hist region, 8 cells x 9 bins. Also emits per-cell
// q = sum(h^2) for the block-norm box filter.
__global__ __launch_bounds__(256) void hog_hist(const float* __restrict__ x,
                                                float* __restrict__ hist,
                                                float* __restrict__ q) {
    __shared__ float lh[4 * 80];
    int t = threadIdx.x;
    int wave = t >> 6, lane = t & 63;
    int wid = blockIdx.x * 4 + wave;
    int crow = wid >> 6;          // cell row 0..511
    int strip = wid & 63;         // 64-col strip 0..63
    int col0 = strip << 6;
    int gc = col0 + lane;

    lh[wave * 80 + lane] = 0.0f;
    if (lane < 16) lh[wave * 80 + 64 + lane] = 0.0f;
    __syncthreads();

    int r0 = (crow << 3) - 1;
    float s[10];
#pragma unroll
    for (int k = 0; k < 10; ++k) {
        int row = r0 + k;
        s[k] = ((unsigned)row < (unsigned)H) ? sqrtf(x[row * W + gc]) : 0.0f;
    }
    // halo columns: same address for all lanes -> broadcast load
    bool has_l = (strip > 0), has_r = (strip < 63);
    float hl[8], hr[8];
#pragma unroll
    for (int j = 0; j < 8; ++j) {
        int gr = (crow << 3) + j;
        hl[j] = has_l ? sqrtf(x[gr * W + (col0 - 1)]) : 0.0f;
        hr[j] = has_r ? sqrtf(x[gr * W + (col0 + 64)]) : 0.0f;
    }
    bool gx_ok = (gc >= 1) && (gc <= W - 2);
    int cellbase = wave * 80 + (lane >> 3) * 9;

#pragma unroll
    for (int j = 0; j < 8; ++j) {
        int gr = (crow << 3) + j;
        float sc = s[j + 1];
        float sl = __shfl_up(sc, 1, 64);
        float sr = __shfl_down(sc, 1, 64);
        if (lane == 0)  sl = hl[j];
        if (lane == 63) sr = hr[j];
        float gx = gx_ok ? (sr - sl) : 0.0f;
        float gy = (gr >= 1 && gr <= H - 2) ? (s[j + 2] - s[j]) : 0.0f;
        int bin = bin_pixel(gy, gx);
        float mag = sqrtf(fmaf(gy, gy, gx * gx));   // value-level only
        if (bin < ORI) atomicAdd(&lh[cellbase + bin], mag);
    }
    __syncthreads();

    // write 72 hist floats per wave (coalesced) + 8 q values
    int base = crow * (NC * ORI) + strip * 72;
    hist[base + lane] = lh[wave * 80 + lane] * (1.0f / 64.0f);
    if (lane < 8) {
        hist[base + 64 + lane] = lh[wave * 80 + 64 + lane] * (1.0f / 64.0f);
        float qq = 0.0f;
#pragma unroll
        for (int o = 0; o < 9; ++o) {
            float h = lh[wave * 80 + lane * 9 + o] * (1.0f / 64.0f);
            qq = fmaf(h, h, qq);
        }
        q[crow * NC + strip * 8 + lane] = qq;
    }
}

// Kernel B: inv(i,j) = rsqrt(3x3 box-sum of q + EPS^2)
__global__ __launch_bounds__(256) void hog_inv(const float* __restrict__ q,
                                               float* __restrict__ inv) {
    int t = blockIdx.x * 256 + threadIdx.x;
    if (t >= NB * NB) return;
    int i = t / NB;
    int j = t - i * NB;
    float ssq = 0.0f;
#pragma unroll
    for (int bi = 0; bi < 3; ++bi)
#pragma unroll
        for (int bj = 0; bj < 3; ++bj)
            ssq += q[(i + bi) * NC + (j + bj)];
    inv[t] = 1.0f / sqrtf(ssq + 1e-10f);
}

// Kernel C: thread per output element, coalesced stores, no reduction.
__global__ __launch_bounds__(256) void hog_norm(const float* __restrict__ hist,
                                                const float* __restrict__ inv,
                                                float* __restrict__ out, int n) {
    int k = blockIdx.x * 256 + threadIdx.x;
    if (k >= n) return;
    int pidx = k / 81;
    int e = k - pidx * 81;
    int i = pidx / NB;
    int j = pidx - i * NB;
    int bi = e / 27;
    int r = e - bi * 27;
    int bj = r / 9;
    int o = r - bj * 9;
    out[k] = hist[((i + bi) * NC + (j + bj)) * ORI + o] * inv[pidx];
}

extern "C" void kernel_launch(void* const* d_in, const int* in_sizes, int n_in,
                              void* d_out, int out_size, void* d_ws, size_t ws_size,
                              hipStream_t stream) {
    const float* x = (const float*)d_in[0];
    float* out = (float*)d_out;
    float* hist = (float*)d_ws;                     // 9.44 MB
    float* inv  = hist + NCELLS * ORI;              // 1.04 MB
    // q (1 MB) parked in d_out's tail: written by A, consumed by B, then
    // fully overwritten by C's real outputs. Keeps ws at the proven 10.5 MB.
    float* q = out + (NOUT - NCELLS);

    hog_hist<<<(NC * 64) / 4, 256, 0, stream>>>(x, hist, q);   // 8192 blocks
    hog_inv<<<(NB * NB + 255) / 256, 256, 0, stream>>>(q, inv);
    hog_norm<<<(out_size + 255) / 256, 256, 0, stream>>>(hist, inv, out, out_size);
}

// Round 9
// 146.704 us; speedup vs baseline: 1.0987x; 1.0987x over previous
//
#include <hip/hip_runtime.h>
#include <math.h>

#define H 4096
#define W 4096
#define NC 512            // cells per dim (H/8)
#define NB 510            // blocks per dim (NC - 3 + 1)
#define ORI 9
#define NCELLS (NC * NC)  // 262144
#define NOUT (NB * NB * 81)  // 21068100

// ---- glibc flt-32 atanf/atan2f replication (fdlibm; pre-2.40 glibc) ----
// Used only on the rare near-boundary fallback path; must stay bit-exact.
__device__ __constant__ float c_atanhi[4] = {
    4.6364760399e-01f, 7.8539812565e-01f, 9.8279368877e-01f, 1.5707962513e+00f,
};
__device__ __constant__ float c_atanlo[4] = {
    5.0121582440e-09f, 3.7748947079e-08f, 3.4473217170e-08f, 7.5497894159e-08f,
};

__device__ float fdlibm_atanf(float x) {
#pragma clang fp contract(off)
    const float one = 1.0f;
    const float aT0  = (float) 3.33333333333329318027e-01;
    const float aT1  = (float)-1.99999999998764832476e-01;
    const float aT2  = (float) 1.42857142725034663711e-01;
    const float aT3  = (float)-1.11111104054623557880e-01;
    const float aT4  = (float) 9.09088713343650656196e-02;
    const float aT5  = (float)-7.69187620504482999495e-02;
    const float aT6  = (float) 6.66107313738753120669e-02;
    const float aT7  = (float)-5.83357013379057348645e-02;
    const float aT8  = (float) 4.97687799461593236017e-02;
    const float aT9  = (float)-3.65315727442169155270e-02;
    const float aT10 = (float) 1.62858201153657823623e-02;
    int hx = __float_as_int(x);
    int ix = hx & 0x7fffffff;
    int id;
    if (ix >= 0x4c800000) {
        if (ix > 0x7f800000) return x + x;
        float r = c_atanhi[3] + c_atanlo[3];
        return (hx > 0) ? r : -r;
    }
    if (ix < 0x3ee00000) {
        if (ix < 0x31000000) return x;
        id = -1;
    } else {
        x = fabsf(x);
        if (ix < 0x3f980000) {
            if (ix < 0x3f300000) { id = 0; x = (2.0f * x - one) / (2.0f + x); }
            else                 { id = 1; x = (x - one) / (x + one); }
        } else {
            if (ix < 0x401c0000) { id = 2; x = (x - 1.5f) / (one + 1.5f * x); }
            else                 { id = 3; x = -1.0f / x; }
        }
    }
    float z = x * x;
    float w = z * z;
    float s1 = z * (aT0 + w * (aT2 + w * (aT4 + w * (aT6 + w * (aT8 + w * aT10)))));
    float s2 = w * (aT1 + w * (aT3 + w * (aT5 + w * (aT7 + w * aT9))));
    if (id < 0) return x - x * (s1 + s2);
    z = c_atanhi[id] - ((x * (s1 + s2) - c_atanlo[id]) - x);
    return (hx < 0) ? -z : z;
}

__device__ float fdlibm_atan2f(float y, float x) {
#pragma clang fp contract(off)
    const float tiny   = 1.0e-30f;
    const float pi     = 3.1415927410e+00f;
    const float pi_lo  = -8.7422776573e-08f;
    const float pi_o_2 = 1.5707963705e+00f;
    int hx = __float_as_int(x), ix = hx & 0x7fffffff;
    int hy = __float_as_int(y), iy = hy & 0x7fffffff;
    if (ix > 0x7f800000 || iy > 0x7f800000) return x + y;
    if (hx == 0x3f800000) return fdlibm_atanf(y);
    int m = ((hy >> 31) & 1) | ((hx >> 30) & 2);
    if (iy == 0) {
        switch (m) {
            case 0: case 1: return y;
            case 2: return pi + tiny;
            default: return -pi - tiny;
        }
    }
    if (ix == 0) return (hy < 0) ? -pi_o_2 - tiny : pi_o_2 + tiny;
    if (ix == 0x7f800000) {
        if (iy == 0x7f800000) {
            switch (m) {
                case 0: return pi_o_2 * 0.5f + tiny;
                case 1: return -(pi_o_2 * 0.5f) - tiny;
                case 2: return 1.5f * pi_o_2 + tiny;
                default: return -(1.5f * pi_o_2) - tiny;
            }
        } else {
            switch (m) {
                case 0: return 0.0f;
                case 1: return -0.0f;
                case 2: return pi + tiny;
                default: return -pi - tiny;
            }
        }
    }
    if (iy == 0x7f800000) return (hy < 0) ? -pi_o_2 - tiny : pi_o_2 + tiny;
    int k = (iy - ix) >> 23;
    float z;
    if (k > 26) { z = pi_o_2 + 0.5f * pi_lo; m &= 1; }
    else if (k < -26 && hx < 0) z = 0.0f;
    else z = fdlibm_atanf(fabsf(y / x));
    switch (m) {
        case 0: return z;
        case 1: return -z;
        case 2: return pi - (z - pi_lo);
        default: return (z - pi_lo) - pi;
    }
}

// Exact-replica binning (slow path). Returns 0..8, or 9 == excluded (m==180 quirk).
__device__ __noinline__ int slow_bin(float gy, float gx) {
#pragma clang fp contract(off)
    float ang = fdlibm_atan2f(gy, gx);
    const float RAD2DEG = (float)(180.0 / 3.14159265358979323846264338328);
    float deg = ang * RAD2DEG;
    float m = fmodf(deg, 180.0f);
    if (m < 0.0f) m += 180.0f;
    int bin = (int)(m / 20.0f);
    if (bin < 9 && m >= (float)((bin + 1) * 20)) bin++;
    else if (bin > 0 && m < (float)(bin * 20)) bin--;
    return bin;
}

// Kernel A: block = 64x32 px tile (8x4 cells). sqrt staged once in LDS (one
// barrier total); thread = 8-px horizontal run of one cell-row; lh wave-private.
// Tangent-threshold binning (4 fma + 4 cmp) with bit-exact fallback guard.
__global__ __launch_bounds__(256) void hog_hist(const float* __restrict__ x,
                                                float* __restrict__ hist,
                                                float* __restrict__ q) {
    __shared__ __align__(16) float S[34 * 68];  // LDS col L = image col col0+L-1
    __shared__ float lh[4 * 72];                // per-wave 8 cells x 9 bins
    int t = threadIdx.x;
    int tcol = blockIdx.x & 63;
    int trow = blockIdx.x >> 6;
    int col0 = tcol << 6;
    int row0 = trow << 5;

    lh[t] = 0.0f;                    // covers 0..255
    if (t < 32) lh[256 + t] = 0.0f;  // covers 256..287

    // stage interior cols (coalesced) — 34 rows x 64 cols
    for (int k = 0; k < 9; ++k) {
        int idx = t + (k << 8);
        if (idx < 34 * 64) {
            int r = idx >> 6, c = idx & 63;
            int grow = row0 - 1 + r;
            float v = ((unsigned)grow < (unsigned)H)
                        ? sqrtf(x[grow * W + col0 + c]) : 0.0f;   // IEEE-exact
            S[r * 68 + c + 1] = v;
        }
    }
    // halo columns
    if (t < 34) {
        int grow = row0 - 1 + t;
        float v = ((unsigned)grow < (unsigned)H && col0 >= 1)
                    ? sqrtf(x[grow * W + col0 - 1]) : 0.0f;
        S[t * 68] = v;
    } else if (t >= 64 && t < 98) {
        int r = t - 64;
        int grow = row0 - 1 + r;
        float v = ((unsigned)grow < (unsigned)H && col0 + 64 < W)
                    ? sqrtf(x[grow * W + col0 + 64]) : 0.0f;
        S[r * 68 + 65] = v;
    }
    __syncthreads();   // the only barrier

    int cell = t & 7;
    int row  = t >> 3;               // 0..31
    int w    = t >> 6;
    int grow = row0 + row;
    int gc0  = col0 + (cell << 3);
    bool row_ok = (grow >= 1) && (grow <= H - 2);   // thread-uniform

    const float4* Sv = (const float4*)S;
    int fa = row * 17 + 2 * cell;            // above row (float4 units)
    float A[12], O[12], B[12];
    *(float4*)&A[0] = Sv[fa];     *(float4*)&A[4] = Sv[fa + 1];  *(float4*)&A[8] = Sv[fa + 2];
    *(float4*)&O[0] = Sv[fa + 17];*(float4*)&O[4] = Sv[fa + 18]; *(float4*)&O[8] = Sv[fa + 19];
    *(float4*)&B[0] = Sv[fa + 34];*(float4*)&B[4] = Sv[fa + 35]; *(float4*)&B[8] = Sv[fa + 36];

    const float T1 = (float) 0.36397023426620236135;  // tan20
    const float T2 = (float) 0.83909963117728001176;  // tan40
    const float T3 = (float) 1.73205080756887729353;  // tan60
    const float T4 = (float) 5.67128181961771110517;  // tan80
    float* lw = &lh[w * 72 + cell * 9];

#pragma unroll
    for (int i = 0; i < 8; ++i) {
        float gy = row_ok ? (B[i + 1] - A[i + 1]) : 0.0f;
        unsigned gcu = (unsigned)(gc0 + i);
        float gx = (gcu - 1u < (unsigned)(W - 2)) ? (O[i + 2] - O[i]) : 0.0f;

        float a = fabsf(gy), b = fabsf(gx);
        float d1 = fmaf(b, -T1, a);
        float d2 = fmaf(b, -T2, a);
        float d3 = fmaf(b, -T3, a);
        float d4 = fmaf(b, -T4, a);
        int cnt = (d1 > 0.0f) + (d2 > 0.0f) + (d3 > 0.0f) + (d4 > 0.0f);
        bool opp = ((__float_as_int(gy) ^ __float_as_int(gx)) < 0);
        int bin = opp ? 8 - cnt : cnt;

        // guard: near 20..160-deg boundaries or near-horizontal (incl m==180 quirk)
        float cm = fminf(fminf(fabsf(d1), fabsf(d2)), fminf(fabsf(d3), fabsf(d4)));
        cm = fminf(cm, a);
        if (cm < 1e-5f * (a + b)) bin = slow_bin(gy, gx);

        float mag = __builtin_amdgcn_sqrtf(fmaf(gy, gy, gx * gx)); // value-level only
        if (bin < ORI) atomicAdd(&lw[bin], mag);
    }

    // epilogue: wave-private lh -> hist (+ per-cell q); no second barrier needed.
    // FIX (r8 bug): lane is 0..63, so elements 64..71 of the 72-element slice
    // need an explicit second write — r8 left them poisoned (absmax 0.387).
    int lane = t & 63;
    int gcr = (row0 >> 3) + w;                       // global cell row
    int cbase = gcr * (NC * ORI) + tcol * 8 * ORI;
    hist[cbase + lane] = lh[w * 72 + lane] * (1.0f / 64.0f);
    if (lane < 8) {
        hist[cbase + 64 + lane] = lh[w * 72 + 64 + lane] * (1.0f / 64.0f);
        float qq = 0.0f;
#pragma unroll
        for (int o = 0; o < 9; ++o) {
            float h = lh[w * 72 + lane * 9 + o] * (1.0f / 64.0f);
            qq = fmaf(h, h, qq);
        }
        q[gcr * NC + tcol * 8 + lane] = qq;
    }
}

// Kernel B: inv(i,j) = rsqrt(3x3 box-sum of q + EPS^2)
__global__ __launch_bounds__(256) void hog_inv(const float* __restrict__ q,
                                               float* __restrict__ inv) {
    int t = blockIdx.x * 256 + threadIdx.x;
    if (t >= NB * NB) return;
    int i = t / NB;
    int j = t - i * NB;
    float ssq = 0.0f;
#pragma unroll
    for (int bi = 0; bi < 3; ++bi)
#pragma unroll
        for (int bj = 0; bj < 3; ++bj)
            ssq += q[(i + bi) * NC + (j + bj)];
    inv[t] = 1.0f / sqrtf(ssq + 1e-10f);
}

// Kernel C: thread per output element, coalesced stores.
__global__ __launch_bounds__(256) void hog_norm(const float* __restrict__ hist,
                                                const float* __restrict__ inv,
                                                float* __restrict__ out, int n) {
    int k = blockIdx.x * 256 + threadIdx.x;
    if (k >= n) return;
    int pidx = k / 81;
    int e = k - pidx * 81;
    int i = pidx / NB;
    int j = pidx - i * NB;
    int bi = e / 27;
    int r = e - bi * 27;
    int bj = r / 9;
    int o = r - bj * 9;
    out[k] = hist[((i + bi) * NC + (j + bj)) * ORI + o] * inv[pidx];
}

extern "C" void kernel_launch(void* const* d_in, const int* in_sizes, int n_in,
                              void* d_out, int out_size, void* d_ws, size_t ws_size,
                              hipStream_t stream) {
    const float* x = (const float*)d_in[0];
    float* out = (float*)d_out;
    float* hist = (float*)d_ws;                     // 9.44 MB
    float* inv  = hist + NCELLS * ORI;              // 1.04 MB
    // q (1 MB) parked in d_out's tail: written by A, consumed by B, then
    // fully overwritten by C (proven in round 7).
    float* q = out + (NOUT - NCELLS);

    hog_hist<<<64 * 128, 256, 0, stream>>>(x, hist, q);
    hog_inv<<<(NB * NB + 255) / 256, 256, 0, stream>>>(q, inv);
    hog_norm<<<(out_size + 255) / 256, 256, 0, stream>>>(hist, inv, out, out_size);
}

// Round 10
// 141.715 us; speedup vs baseline: 1.1374x; 1.0352x over previous
//
#include <hip/hip_runtime.h>
#include <math.h>

#define H 4096
#define W 4096
#define NC 512            // cells per dim (H/8)
#define NB 510            // blocks per dim (NC - 3 + 1)
#define ORI 9
#define NCELLS (NC * NC)  // 262144
#define NOUT (NB * NB * 81)  // 21068100

// ---- glibc flt-32 atanf/atan2f replication (fdlibm; pre-2.40 glibc) ----
// Used only on the rare near-boundary fallback path; must stay bit-exact.
__device__ __constant__ float c_atanhi[4] = {
    4.6364760399e-01f, 7.8539812565e-01f, 9.8279368877e-01f, 1.5707962513e+00f,
};
__device__ __constant__ float c_atanlo[4] = {
    5.0121582440e-09f, 3.7748947079e-08f, 3.4473217170e-08f, 7.5497894159e-08f,
};

__device__ float fdlibm_atanf(float x) {
#pragma clang fp contract(off)
    const float one = 1.0f;
    const float aT0  = (float) 3.33333333333329318027e-01;
    const float aT1  = (float)-1.99999999998764832476e-01;
    const float aT2  = (float) 1.42857142725034663711e-01;
    const float aT3  = (float)-1.11111104054623557880e-01;
    const float aT4  = (float) 9.09088713343650656196e-02;
    const float aT5  = (float)-7.69187620504482999495e-02;
    const float aT6  = (float) 6.66107313738753120669e-02;
    const float aT7  = (float)-5.83357013379057348645e-02;
    const float aT8  = (float) 4.97687799461593236017e-02;
    const float aT9  = (float)-3.65315727442169155270e-02;
    const float aT10 = (float) 1.62858201153657823623e-02;
    int hx = __float_as_int(x);
    int ix = hx & 0x7fffffff;
    int id;
    if (ix >= 0x4c800000) {
        if (ix > 0x7f800000) return x + x;
        float r = c_atanhi[3] + c_atanlo[3];
        return (hx > 0) ? r : -r;
    }
    if (ix < 0x3ee00000) {
        if (ix < 0x31000000) return x;
        id = -1;
    } else {
        x = fabsf(x);
        if (ix < 0x3f980000) {
            if (ix < 0x3f300000) { id = 0; x = (2.0f * x - one) / (2.0f + x); }
            else                 { id = 1; x = (x - one) / (x + one); }
        } else {
            if (ix < 0x401c0000) { id = 2; x = (x - 1.5f) / (one + 1.5f * x); }
            else                 { id = 3; x = -1.0f / x; }
        }
    }
    float z = x * x;
    float w = z * z;
    float s1 = z * (aT0 + w * (aT2 + w * (aT4 + w * (aT6 + w * (aT8 + w * aT10)))));
    float s2 = w * (aT1 + w * (aT3 + w * (aT5 + w * (aT7 + w * aT9))));
    if (id < 0) return x - x * (s1 + s2);
    z = c_atanhi[id] - ((x * (s1 + s2) - c_atanlo[id]) - x);
    return (hx < 0) ? -z : z;
}

__device__ float fdlibm_atan2f(float y, float x) {
#pragma clang fp contract(off)
    const float tiny   = 1.0e-30f;
    const float pi     = 3.1415927410e+00f;
    const float pi_lo  = -8.7422776573e-08f;
    const float pi_o_2 = 1.5707963705e+00f;
    int hx = __float_as_int(x), ix = hx & 0x7fffffff;
    int hy = __float_as_int(y), iy = hy & 0x7fffffff;
    if (ix > 0x7f800000 || iy > 0x7f800000) return x + y;
    if (hx == 0x3f800000) return fdlibm_atanf(y);
    int m = ((hy >> 31) & 1) | ((hx >> 30) & 2);
    if (iy == 0) {
        switch (m) {
            case 0: case 1: return y;
            case 2: return pi + tiny;
            default: return -pi - tiny;
        }
    }
    if (ix == 0) return (hy < 0) ? -pi_o_2 - tiny : pi_o_2 + tiny;
    if (ix == 0x7f800000) {
        if (iy == 0x7f800000) {
            switch (m) {
                case 0: return pi_o_2 * 0.5f + tiny;
                case 1: return -(pi_o_2 * 0.5f) - tiny;
                case 2: return 1.5f * pi_o_2 + tiny;
                default: return -(1.5f * pi_o_2) - tiny;
            }
        } else {
            switch (m) {
                case 0: return 0.0f;
                case 1: return -0.0f;
                case 2: return pi + tiny;
                default: return -pi - tiny;
            }
        }
    }
    if (iy == 0x7f800000) return (hy < 0) ? -pi_o_2 - tiny : pi_o_2 + tiny;
    int k = (iy - ix) >> 23;
    float z;
    if (k > 26) { z = pi_o_2 + 0.5f * pi_lo; m &= 1; }
    else if (k < -26 && hx < 0) z = 0.0f;
    else z = fdlibm_atanf(fabsf(y / x));
    switch (m) {
        case 0: return z;
        case 1: return -z;
        case 2: return pi - (z - pi_lo);
        default: return (z - pi_lo) - pi;
    }
}

// Exact-replica binning (slow path). Returns 0..8, or 9 == excluded (m==180 quirk).
__device__ __noinline__ int slow_bin(float gy, float gx) {
#pragma clang fp contract(off)
    float ang = fdlibm_atan2f(gy, gx);
    const float RAD2DEG = (float)(180.0 / 3.14159265358979323846264338328);
    float deg = ang * RAD2DEG;
    float m = fmodf(deg, 180.0f);
    if (m < 0.0f) m += 180.0f;
    int bin = (int)(m / 20.0f);
    if (bin < 9 && m >= (float)((bin + 1) * 20)) bin++;
    else if (bin > 0 && m < (float)(bin * 20)) bin--;
    return bin;
}

// Kernel A: block = 64x32 px tile (8x4 cells). Load-first staging (all global
// loads in flight before sqrt/ds_write), sqrt tile in LDS, one barrier,
// thread = 8-px cell-row run via 9x ds_read_b128, tangent-threshold binning.
// __launch_bounds__(256,4): VGPR cap 128 — r9's VGPR=20 serialized everything.
__global__ __launch_bounds__(256, 4) void hog_hist(const float* __restrict__ x,
                                                   float* __restrict__ hist,
                                                   float* __restrict__ q) {
    __shared__ __align__(16) float S[34 * 68];  // LDS col L = image col col0+L-1
    __shared__ float lh[4 * 72];                // per-wave 8 cells x 9 bins
    int t = threadIdx.x;
    int tcol = blockIdx.x & 63;
    int trow = blockIdx.x >> 6;
    int col0 = tcol << 6;
    int row0 = trow << 5;

    lh[t] = 0.0f;
    if (t < 32) lh[256 + t] = 0.0f;

    // ---- load phase: ALL global loads issued before any sqrt/LDS write ----
    const float* xb = x + (row0 - 1) * W + col0;   // tile origin (row -1)
    float v[9];
#pragma unroll
    for (int k = 0; k < 8; ++k) {
        int idx = t + (k << 8);
        int r = idx >> 6, c = idx & 63;
        bool ok = (k > 0) || (row0 + r > 0);       // only k=0 can hit row -1
        v[k] = ok ? xb[r * W + c] : 0.0f;
    }
    if (t < 128) {                                  // k=8 tail: rows 32..33
        int idx = t + 2048;
        int r = idx >> 6, c = idx & 63;
        v[8] = (row0 - 1 + r < H) ? xb[r * W + c] : 0.0f;
    }
    float vh = 0.0f;                                // halo columns
    if (t < 34) {
        int grow = row0 - 1 + t;
        if ((unsigned)grow < (unsigned)H && col0 >= 1) vh = x[grow * W + col0 - 1];
    } else if (t >= 64 && t < 98) {
        int grow = row0 - 1 + (t - 64);
        if ((unsigned)grow < (unsigned)H && col0 + 64 < W) vh = x[grow * W + col0 + 64];
    }

    // ---- sqrt + LDS write phase ----
#pragma unroll
    for (int k = 0; k < 8; ++k) {
        int idx = t + (k << 8);
        int r = idx >> 6, c = idx & 63;
        S[r * 68 + c + 1] = sqrtf(v[k]);           // IEEE-exact, matches np.sqrt
    }
    if (t < 128) {
        int idx = t + 2048;
        int r = idx >> 6, c = idx & 63;
        S[r * 68 + c + 1] = sqrtf(v[8]);
    }
    if (t < 34) S[t * 68] = sqrtf(vh);
    else if (t >= 64 && t < 98) S[(t - 64) * 68 + 65] = sqrtf(vh);
    __syncthreads();   // the only barrier

    int cell = t & 7;
    int row  = t >> 3;               // 0..31
    int w    = t >> 6;
    int grow = row0 + row;
    int gc0  = col0 + (cell << 3);
    bool row_ok = (grow >= 1) && (grow <= H - 2);

    const float4* Sv = (const float4*)S;
    int fa = row * 17 + 2 * cell;            // above row (float4 units)
    float A[12], O[12], B[12];
    *(float4*)&A[0] = Sv[fa];     *(float4*)&A[4] = Sv[fa + 1];  *(float4*)&A[8] = Sv[fa + 2];
    *(float4*)&O[0] = Sv[fa + 17];*(float4*)&O[4] = Sv[fa + 18]; *(float4*)&O[8] = Sv[fa + 19];
    *(float4*)&B[0] = Sv[fa + 34];*(float4*)&B[4] = Sv[fa + 35]; *(float4*)&B[8] = Sv[fa + 36];

    const float T1 = (float) 0.36397023426620236135;  // tan20
    const float T2 = (float) 0.83909963117728001176;  // tan40
    const float T3 = (float) 1.73205080756887729353;  // tan60
    const float T4 = (float) 5.67128181961771110517;  // tan80
    float* lw = &lh[w * 72 + cell * 9];

#pragma unroll
    for (int i = 0; i < 8; ++i) {
        float gy = row_ok ? (B[i + 1] - A[i + 1]) : 0.0f;
        unsigned gcu = (unsigned)(gc0 + i);
        float gx = (gcu - 1u < (unsigned)(W - 2)) ? (O[i + 2] - O[i]) : 0.0f;

        float a = fabsf(gy), b = fabsf(gx);
        float d1 = fmaf(b, -T1, a);
        float d2 = fmaf(b, -T2, a);
        float d3 = fmaf(b, -T3, a);
        float d4 = fmaf(b, -T4, a);
        int cnt = (d1 > 0.0f) + (d2 > 0.0f) + (d3 > 0.0f) + (d4 > 0.0f);
        bool opp = ((__float_as_int(gy) ^ __float_as_int(gx)) < 0);
        int bin = opp ? 8 - cnt : cnt;

        float cm = fminf(fminf(fabsf(d1), fabsf(d2)), fminf(fabsf(d3), fabsf(d4)));
        cm = fminf(cm, a);
        if (cm < 1e-5f * (a + b)) bin = slow_bin(gy, gx);

        float mag = __builtin_amdgcn_sqrtf(fmaf(gy, gy, gx * gx)); // value-level only
        if (bin < ORI) atomicAdd(&lw[bin], mag);
    }

    // epilogue: wave-private lh -> hist (+ per-cell q); includes r8's 64..71 fix.
    int lane = t & 63;
    int gcr = (row0 >> 3) + w;                       // global cell row
    int cbase = gcr * (NC * ORI) + tcol * 8 * ORI;
    hist[cbase + lane] = lh[w * 72 + lane] * (1.0f / 64.0f);
    if (lane < 8) {
        hist[cbase + 64 + lane] = lh[w * 72 + 64 + lane] * (1.0f / 64.0f);
        float qq = 0.0f;
#pragma unroll
        for (int o = 0; o < 9; ++o) {
            float h = lh[w * 72 + lane * 9 + o] * (1.0f / 64.0f);
            qq = fmaf(h, h, qq);
        }
        q[gcr * NC + tcol * 8 + lane] = qq;
    }
}

// Kernel B: inv(i,j) = rsqrt(3x3 box-sum of q + EPS^2)
__global__ __launch_bounds__(256) void hog_inv(const float* __restrict__ q,
                                               float* __restrict__ inv) {
    int t = blockIdx.x * 256 + threadIdx.x;
    if (t >= NB * NB) return;
    int i = t / NB;
    int j = t - i * NB;
    float ssq = 0.0f;
#pragma unroll
    for (int bi = 0; bi < 3; ++bi)
#pragma unroll
        for (int bj = 0; bj < 3; ++bj)
            ssq += q[(i + bi) * NC + (j + bj)];
    inv[t] = 1.0f / sqrtf(ssq + 1e-10f);
}

// Kernel C: thread per output element, coalesced stores.
__global__ __launch_bounds__(256) void hog_norm(const float* __restrict__ hist,
                                                const float* __restrict__ inv,
                                                float* __restrict__ out, int n) {
    int k = blockIdx.x * 256 + threadIdx.x;
    if (k >= n) return;
    int pidx = k / 81;
    int e = k - pidx * 81;
    int i = pidx / NB;
    int j = pidx - i * NB;
    int bi = e / 27;
    int r = e - bi * 27;
    int bj = r / 9;
    int o = r - bj * 9;
    out[k] = hist[((i + bi) * NC + (j + bj)) * ORI + o] * inv[pidx];
}

extern "C" void kernel_launch(void* const* d_in, const int* in_sizes, int n_in,
                              void* d_out, int out_size, void* d_ws, size_t ws_size,
                              hipStream_t stream) {
    const float* x = (const float*)d_in[0];
    float* out = (float*)d_out;
    float* hist = (float*)d_ws;                     // 9.44 MB
    float* inv  = hist + NCELLS * ORI;              // 1.04 MB
    // q (1 MB) parked in d_out's tail: written by A, consumed by B, then
    // fully overwritten by C (proven since round 7).
    float* q = out + (NOUT - NCELLS);

    hog_hist<<<64 * 128, 256, 0, stream>>>(x, hist, q);
    hog_inv<<<(NB * NB + 255) / 256, 256, 0, stream>>>(q, inv);
    hog_norm<<<(out_size + 255) / 256, 256, 0, stream>>>(hist, inv, out, out_size);
}